// Round 7
// baseline (1678.153 us; speedup 1.0000x reference)
//
#include <hip/hip_runtime.h>
#include <hip/hip_bf16.h>
#include <cstdint>

constexpr int Mx = 8192;
constexpr int Kx = 4096;
constexpr int Nx = 16384;
constexpr long W_ELEMS = (long)Nx * Kx;      // 67108864
constexpr long X_ELEMS = (long)Mx * Kx;      // 33554432
constexpr int KB = Kx / 2;                   // 2048 packed fp4 bytes per row

typedef int v4i __attribute__((ext_vector_type(4)));
typedef int v8i __attribute__((ext_vector_type(8)));
typedef float v16f __attribute__((ext_vector_type(16)));

#define GLOBAL_AS(p) ((const __attribute__((address_space(1))) void*)(p))
#define LDS_AS(p)    ((__attribute__((address_space(3))) void*)(p))

// ---------------- Pass 1: sum |W| (deterministic two-level tree) ----------------
__global__ __launch_bounds__(256) void absum_kernel(const float4* __restrict__ W4,
                                                    double* __restrict__ partials) {
    int t = threadIdx.x;
    long base = (long)blockIdx.x * 8192;
    double s = 0.0;
#pragma unroll 4
    for (int i = 0; i < 32; ++i) {
        float4 v = W4[base + (long)i * 256 + t];
        s += (double)fabsf(v.x) + (double)fabsf(v.y) +
             (double)fabsf(v.z) + (double)fabsf(v.w);
    }
    __shared__ double sm[256];
    sm[t] = s;
    __syncthreads();
    for (int off = 128; off > 0; off >>= 1) {
        if (t < off) sm[t] += sm[t + off];
        __syncthreads();
    }
    if (t == 0) partials[blockIdx.x] = sm[0];
}

__global__ __launch_bounds__(256) void finalize_kernel(const double* __restrict__ partials,
                                                       float* __restrict__ thr) {
    int t = threadIdx.x;
    double s = 0.0;
#pragma unroll
    for (int i = 0; i < 8; ++i) s += partials[(long)i * 256 + t];
    __shared__ double sm[256];
    sm[t] = s;
    __syncthreads();
    for (int off = 128; off > 0; off >>= 1) {
        if (t < off) sm[t] += sm[t + off];
        __syncthreads();
    }
    if (t == 0) {
        double gamma = sm[0] / (double)W_ELEMS + 1e-6;
        *thr = (float)(0.5 * gamma);
    }
}

// fp4 e2m1 encode of ternary: +1 -> 0x2, -1 -> 0xA, 0 -> 0x0
__device__ __forceinline__ uint32_t enc_t(float v, float thr) {
    return (fabsf(v) > thr) ? ((v > 0.f) ? 0x2u : 0xAu) : 0x0u;
}

__device__ __forceinline__ uint32_t pack8(float4 a, float4 b, float thr) {
    return enc_t(a.x, thr)        | (enc_t(a.y, thr) << 4)  |
          (enc_t(a.z, thr) << 8)  | (enc_t(a.w, thr) << 12) |
          (enc_t(b.x, thr) << 16) | (enc_t(b.y, thr) << 20) |
          (enc_t(b.z, thr) << 24) | (enc_t(b.w, thr) << 28);
}

// ---------------- Pass 2: quantize W -> packed fp4 (32 elems/thread) -----------
__global__ __launch_bounds__(256) void quantw_kernel(const float4* __restrict__ W4,
                                                     uint4* __restrict__ out,
                                                     const float* __restrict__ thrp) {
    float thr = *thrp;
    long gt = (long)blockIdx.x * 256 + threadIdx.x;
    uint32_t d0 = pack8(W4[gt * 8 + 0], W4[gt * 8 + 1], thr);
    uint32_t d1 = pack8(W4[gt * 8 + 2], W4[gt * 8 + 3], thr);
    uint32_t d2 = pack8(W4[gt * 8 + 4], W4[gt * 8 + 5], thr);
    uint32_t d3 = pack8(W4[gt * 8 + 6], W4[gt * 8 + 7], thr);
    out[gt] = make_uint4(d0, d1, d2, d3);
}

// ---------------- Pass 3: binarize x -> packed fp4 sign ------------------------
__global__ __launch_bounds__(256) void quantx_kernel(const float4* __restrict__ X4,
                                                     uint4* __restrict__ out) {
    long gt = (long)blockIdx.x * 256 + threadIdx.x;
    uint32_t d0 = pack8(X4[gt * 8 + 0], X4[gt * 8 + 1], 0.f);
    uint32_t d1 = pack8(X4[gt * 8 + 2], X4[gt * 8 + 3], 0.f);
    uint32_t d2 = pack8(X4[gt * 8 + 4], X4[gt * 8 + 5], 0.f);
    uint32_t d3 = pack8(X4[gt * 8 + 6], X4[gt * 8 + 7], 0.f);
    out[gt] = make_uint4(d0, d1, d2, d3);
}

// ---------------- Pass 4: fp4 GEMM, 256^2 tile, mfma_scale 32x32x64 ------------
// One barrier per K-tile (32 phases).  Per phase: read h0 frags, issue stage of
// K-tile tau+3 (ring 8 x 16KB slots, unit 2m=A 2m+1=B of tile m), MFMA h0,
// read h1 frags, MFMA h1, counted vmcnt, s_barrier.
// Safety (single barrier): stage at phase tau overwrites units 2tau-2,2tau-1,
// last read during phase tau-1 BEFORE barrier(tau-1); stage issues AFTER it.
// Data-ready: per-wave vmcnt(8) before barrier(tau) => all chunks of units
// <=2tau+3 landed chip-wide before any wave enters phase tau+1.
// vmcnt: tau<=28 -> 8 (units 2tau+4..2tau+7 in flight); 29 -> 4; 30 -> 0.
__global__ __launch_bounds__(512) void gemm_fp4(const uint8_t* __restrict__ A,
                                                const uint8_t* __restrict__ B,
                                                float* __restrict__ C) {
    __shared__ __align__(16) uint8_t smem[8 * 16384];   // 128 KiB

    const int t = threadIdx.x;
    const int l = t & 63;
    const int wid = t >> 6;
    const int wm = wid >> 2;          // 0..1
    const int wn = wid & 3;           // 0..3
    const int lr = l & 31;            // row within 32
    const int lh = l >> 5;            // k-chunk selector

    // Bijective XCD swizzle: 2048 wgs % 8 == 0.
    int wg = blockIdx.x;
    int sw = (wg & 7) * 256 + (wg >> 3);
    int bm = sw & 31;                 // 32 M-tiles
    int bn = sw >> 5;                 // 64 N-tiles
    const long m0 = (long)bm * 256;
    const long n0 = (long)bn * 256;

    // Staging: phys chunk cp holds row r = cp>>2, logical col c = (cp&3)^((r>>1)&3).
    // cp0 = t, cp1 = t+512 (row + 128: same XOR since 128 % 4 == 0).
    const int r0s = t >> 2;
    const int cb0 = (((t & 3) ^ ((r0s >> 1) & 3)) << 4);
    const int voff0 = r0s * KB + cb0;            // shared by A and B panels
    const int voff1 = voff0 + 128 * KB;
    const uint8_t* Abase = A + m0 * (long)KB;    // uniform -> SGPR
    const uint8_t* Bbase = B + n0 * (long)KB;    // uniform -> SGPR
    const int lo0 = t * 16, lo1 = t * 16 + 8192;

    // ds_read offsets (swizzled), per k-half h: c = h*2 + lh.
    auto swz = [](int r, int c) {
        return r * 64 + ((c ^ ((r >> 1) & 3)) << 4);
    };
    int offA[2][4], offB[2][2];
#pragma unroll
    for (int h = 0; h < 2; ++h) {
#pragma unroll
        for (int mt = 0; mt < 4; ++mt)
            offA[h][mt] = swz(wm * 128 + mt * 32 + lr, h * 2 + lh);
#pragma unroll
        for (int nt = 0; nt < 2; ++nt)
            offB[h][nt] = swz(wn * 64 + nt * 32 + lr, h * 2 + lh);
    }

    v16f acc[4][2] = {};   // 128 regs (AGPR-eligible)

    // Prologue: stage K-tiles 0..2 (units 0..5, 12 loads); wait units 0,1.
#pragma unroll
    for (int pt = 0; pt < 3; ++pt) {
        long koff = (long)pt * 64;
        __builtin_amdgcn_global_load_lds(GLOBAL_AS(Abase + koff + voff0), LDS_AS(smem + (2 * pt) * 16384 + lo0), 16, 0, 0);
        __builtin_amdgcn_global_load_lds(GLOBAL_AS(Abase + koff + voff1), LDS_AS(smem + (2 * pt) * 16384 + lo1), 16, 0, 0);
        __builtin_amdgcn_global_load_lds(GLOBAL_AS(Bbase + koff + voff0), LDS_AS(smem + (2 * pt + 1) * 16384 + lo0), 16, 0, 0);
        __builtin_amdgcn_global_load_lds(GLOBAL_AS(Bbase + koff + voff1), LDS_AS(smem + (2 * pt + 1) * 16384 + lo1), 16, 0, 0);
    }
    asm volatile("s_waitcnt vmcnt(8)" ::: "memory");
    asm volatile("s_barrier" ::: "memory");

#pragma unroll 4
    for (int tau = 0; tau < 32; ++tau) {
        const int sA = (2 * tau) & 7;
        const int sB = sA + 1;

        // h0 fragment reads
        v4i a0[4], b0[2];
#pragma unroll
        for (int mt = 0; mt < 4; ++mt)
            a0[mt] = *(const v4i*)(smem + sA * 16384 + offA[0][mt]);
#pragma unroll
        for (int nt = 0; nt < 2; ++nt)
            b0[nt] = *(const v4i*)(smem + sB * 16384 + offB[0][nt]);

        // Stage K-tile tau+3 (units 2tau+6 = A, 2tau+7 = B).
        if (tau <= 28) {
            const int slA2 = (2 * tau + 6) & 7;
            const int slB2 = (2 * tau + 7) & 7;
            const long koff = (long)(tau + 3) * 64;
            __builtin_amdgcn_global_load_lds(GLOBAL_AS(Abase + koff + voff0), LDS_AS(smem + slA2 * 16384 + lo0), 16, 0, 0);
            __builtin_amdgcn_global_load_lds(GLOBAL_AS(Abase + koff + voff1), LDS_AS(smem + slA2 * 16384 + lo1), 16, 0, 0);
            __builtin_amdgcn_global_load_lds(GLOBAL_AS(Bbase + koff + voff0), LDS_AS(smem + slB2 * 16384 + lo0), 16, 0, 0);
            __builtin_amdgcn_global_load_lds(GLOBAL_AS(Bbase + koff + voff1), LDS_AS(smem + slB2 * 16384 + lo1), 16, 0, 0);
        }

        // MFMA h0
        {
            v8i b80 = __builtin_shufflevector(b0[0], b0[0], 0, 1, 2, 3, -1, -1, -1, -1);
            v8i b81 = __builtin_shufflevector(b0[1], b0[1], 0, 1, 2, 3, -1, -1, -1, -1);
            __builtin_amdgcn_s_setprio(1);
#pragma unroll
            for (int mt = 0; mt < 4; ++mt) {
                v8i a8 = __builtin_shufflevector(a0[mt], a0[mt], 0, 1, 2, 3, -1, -1, -1, -1);
                acc[mt][0] = __builtin_amdgcn_mfma_scale_f32_32x32x64_f8f6f4(
                    a8, b80, acc[mt][0], 4, 4, 0, 0x7F7F7F7F, 0, 0x7F7F7F7F);
                acc[mt][1] = __builtin_amdgcn_mfma_scale_f32_32x32x64_f8f6f4(
                    a8, b81, acc[mt][1], 4, 4, 0, 0x7F7F7F7F, 0, 0x7F7F7F7F);
            }
            __builtin_amdgcn_s_setprio(0);
        }

        // h1 fragment reads
        v4i a1[4], b1[2];
#pragma unroll
        for (int mt = 0; mt < 4; ++mt)
            a1[mt] = *(const v4i*)(smem + sA * 16384 + offA[1][mt]);
#pragma unroll
        for (int nt = 0; nt < 2; ++nt)
            b1[nt] = *(const v4i*)(smem + sB * 16384 + offB[1][nt]);

        // MFMA h1
        {
            v8i b80 = __builtin_shufflevector(b1[0], b1[0], 0, 1, 2, 3, -1, -1, -1, -1);
            v8i b81 = __builtin_shufflevector(b1[1], b1[1], 0, 1, 2, 3, -1, -1, -1, -1);
            __builtin_amdgcn_s_setprio(1);
#pragma unroll
            for (int mt = 0; mt < 4; ++mt) {
                v8i a8 = __builtin_shufflevector(a1[mt], a1[mt], 0, 1, 2, 3, -1, -1, -1, -1);
                acc[mt][0] = __builtin_amdgcn_mfma_scale_f32_32x32x64_f8f6f4(
                    a8, b80, acc[mt][0], 4, 4, 0, 0x7F7F7F7F, 0, 0x7F7F7F7F);
                acc[mt][1] = __builtin_amdgcn_mfma_scale_f32_32x32x64_f8f6f4(
                    a8, b81, acc[mt][1], 4, 4, 0, 0x7F7F7F7F, 0, 0x7F7F7F7F);
            }
            __builtin_amdgcn_s_setprio(0);
        }

        // Counted wait: units 2tau+4..2tau+7 may stay in flight.
        if (tau <= 28)      asm volatile("s_waitcnt vmcnt(8)" ::: "memory");
        else if (tau == 29) asm volatile("s_waitcnt vmcnt(4)" ::: "memory");
        else if (tau == 30) asm volatile("s_waitcnt vmcnt(0)" ::: "memory");
        asm volatile("s_barrier" ::: "memory");
    }

    // Epilogue: 32x32 C/D layout col = lane&31, row = (reg&3)+8*(reg>>2)+4*(lane>>5).
#pragma unroll
    for (int mt = 0; mt < 4; ++mt) {
        long rbase = m0 + wm * 128 + mt * 32 + 4 * lh;
#pragma unroll
        for (int nt = 0; nt < 2; ++nt) {
            long gcol = n0 + wn * 64 + nt * 32 + lr;
#pragma unroll
            for (int r = 0; r < 16; ++r) {
                long grow = rbase + (r & 3) + 8 * (r >> 2);
                C[grow * Nx + gcol] = acc[mt][nt][r];
            }
        }
    }
}

extern "C" void kernel_launch(void* const* d_in, const int* in_sizes, int n_in,
                              void* d_out, int out_size, void* d_ws, size_t ws_size,
                              hipStream_t stream) {
    const float* x = (const float*)d_in[0];
    const float* weight = (const float*)d_in[1];
    float* out = (float*)d_out;

    // Workspace: xq 16 MB | wq 32 MB | partials 16 KB | thr
    uint8_t* xq = (uint8_t*)d_ws;
    uint8_t* wq = xq + X_ELEMS / 2;
    double* partials = (double*)((char*)d_ws + X_ELEMS / 2 + W_ELEMS / 2);
    float* thr = (float*)((char*)d_ws + X_ELEMS / 2 + W_ELEMS / 2 + 2048 * sizeof(double));

    absum_kernel<<<2048, 256, 0, stream>>>((const float4*)weight, partials);
    finalize_kernel<<<1, 256, 0, stream>>>(partials, thr);
    quantw_kernel<<<8192, 256, 0, stream>>>((const float4*)weight, (uint4*)wq, thr);
    quantx_kernel<<<4096, 256, 0, stream>>>((const float4*)x, (uint4*)xq);
    gemm_fp4<<<2048, 512, 0, stream>>>(xq, wq, out);
}

// Round 8
// 691.317 us; speedup vs baseline: 2.4275x; 2.4275x over previous
//
#include <hip/hip_runtime.h>
#include <hip/hip_bf16.h>
#include <cstdint>

constexpr int Mx = 8192;
constexpr int Kx = 4096;
constexpr int Nx = 16384;
constexpr long W_ELEMS = (long)Nx * Kx;      // 67108864
constexpr long X_ELEMS = (long)Mx * Kx;      // 33554432
constexpr int KB = Kx / 2;                   // 2048 packed fp4 bytes per row

typedef int v4i __attribute__((ext_vector_type(4)));
typedef int v8i __attribute__((ext_vector_type(8)));
typedef float v16f __attribute__((ext_vector_type(16)));

#define GLOBAL_AS(p) ((const __attribute__((address_space(1))) void*)(p))
#define LDS_AS(p)    ((__attribute__((address_space(3))) void*)(p))

template <int P> struct IC { static constexpr int value = P; };

// ---------------- Pass 1: sum |W| (deterministic two-level tree) ----------------
__global__ __launch_bounds__(256) void absum_kernel(const float4* __restrict__ W4,
                                                    double* __restrict__ partials) {
    int t = threadIdx.x;
    long base = (long)blockIdx.x * 8192;
    double s = 0.0;
#pragma unroll 4
    for (int i = 0; i < 32; ++i) {
        float4 v = W4[base + (long)i * 256 + t];
        s += (double)fabsf(v.x) + (double)fabsf(v.y) +
             (double)fabsf(v.z) + (double)fabsf(v.w);
    }
    __shared__ double sm[256];
    sm[t] = s;
    __syncthreads();
    for (int off = 128; off > 0; off >>= 1) {
        if (t < off) sm[t] += sm[t + off];
        __syncthreads();
    }
    if (t == 0) partials[blockIdx.x] = sm[0];
}

__global__ __launch_bounds__(256) void finalize_kernel(const double* __restrict__ partials,
                                                       float* __restrict__ thr) {
    int t = threadIdx.x;
    double s = 0.0;
#pragma unroll
    for (int i = 0; i < 8; ++i) s += partials[(long)i * 256 + t];
    __shared__ double sm[256];
    sm[t] = s;
    __syncthreads();
    for (int off = 128; off > 0; off >>= 1) {
        if (t < off) sm[t] += sm[t + off];
        __syncthreads();
    }
    if (t == 0) {
        double gamma = sm[0] / (double)W_ELEMS + 1e-6;
        *thr = (float)(0.5 * gamma);
    }
}

// fp4 e2m1 encode of ternary: +1 -> 0x2, -1 -> 0xA, 0 -> 0x0
__device__ __forceinline__ uint32_t enc_t(float v, float thr) {
    return (fabsf(v) > thr) ? ((v > 0.f) ? 0x2u : 0xAu) : 0x0u;
}

__device__ __forceinline__ uint32_t pack8(float4 a, float4 b, float thr) {
    return enc_t(a.x, thr)        | (enc_t(a.y, thr) << 4)  |
          (enc_t(a.z, thr) << 8)  | (enc_t(a.w, thr) << 12) |
          (enc_t(b.x, thr) << 16) | (enc_t(b.y, thr) << 20) |
          (enc_t(b.z, thr) << 24) | (enc_t(b.w, thr) << 28);
}

// ---------------- Pass 2: quantize W -> packed fp4 (32 elems/thread) -----------
__global__ __launch_bounds__(256) void quantw_kernel(const float4* __restrict__ W4,
                                                     uint4* __restrict__ out,
                                                     const float* __restrict__ thrp) {
    float thr = *thrp;
    long gt = (long)blockIdx.x * 256 + threadIdx.x;
    uint32_t d0 = pack8(W4[gt * 8 + 0], W4[gt * 8 + 1], thr);
    uint32_t d1 = pack8(W4[gt * 8 + 2], W4[gt * 8 + 3], thr);
    uint32_t d2 = pack8(W4[gt * 8 + 4], W4[gt * 8 + 5], thr);
    uint32_t d3 = pack8(W4[gt * 8 + 6], W4[gt * 8 + 7], thr);
    out[gt] = make_uint4(d0, d1, d2, d3);
}

// ---------------- Pass 3: binarize x -> packed fp4 sign ------------------------
__global__ __launch_bounds__(256) void quantx_kernel(const float4* __restrict__ X4,
                                                     uint4* __restrict__ out) {
    long gt = (long)blockIdx.x * 256 + threadIdx.x;
    uint32_t d0 = pack8(X4[gt * 8 + 0], X4[gt * 8 + 1], 0.f);
    uint32_t d1 = pack8(X4[gt * 8 + 2], X4[gt * 8 + 3], 0.f);
    uint32_t d2 = pack8(X4[gt * 8 + 4], X4[gt * 8 + 5], 0.f);
    uint32_t d3 = pack8(X4[gt * 8 + 6], X4[gt * 8 + 7], 0.f);
    out[gt] = make_uint4(d0, d1, d2, d3);
}

// ---------------- Pass 4: fp4 GEMM, 128^2 tile, mfma_scale 32x32x64 ------------
// EXACT r6 schedule (proven 384 us / absmax 0), re-parameterized to a 4-wave
// 128x128 block so that TWO blocks co-reside per CU (64 KiB LDS each, acc=64
// regs).  Two independent barrier domains per CU: one block's ds_read burst
// overlaps the other block's MFMA burst on the same SIMDs.
// Unit = one operand K-tile = 128 rows x 64 B = 8 KB = 1 slot; ring 8 slots.
// Units S(j): tile j>>1, j&1 (0=A,1=B).  Phase (tau,h): read 4 frags (k-half
// h), stage unit 2tau+h+5, B1, 4 MFMA, (h==1: counted vmcnt), B2.
// vmcnt(6): 3 units (6 loads/thread) in flight; tail 4 then 0.
__global__ __launch_bounds__(256, 2) void gemm_fp4(const uint8_t* __restrict__ A,
                                                   const uint8_t* __restrict__ B,
                                                   float* __restrict__ C) {
    __shared__ __align__(16) uint8_t smem[8 * 8192];   // 64 KiB

    const int t = threadIdx.x;
    const int l = t & 63;
    const int wid = t >> 6;
    const int wm = wid >> 1;          // 0..1
    const int wn = wid & 1;           // 0..1
    const int lr = l & 31;            // row within 32
    const int lh = l >> 5;            // k-chunk selector

    // Bijective XCD swizzle: 8192 wgs % 8 == 0.
    int wg = blockIdx.x;
    int sw = (wg & 7) * 1024 + (wg >> 3);
    int bm = sw & 63;                 // 64 M-tiles
    int bn = sw >> 6;                 // 128 N-tiles
    const long m0 = (long)bm * 128;
    const long n0 = (long)bn * 128;

    // Staging: unit = 512 chunks of 16B; thread t takes chunks {t, t+256}.
    // Phys chunk cp holds row r = cp>>2, logical col c = (cp&3)^((r>>1)&3).
    // cp1 = t+256 -> row + 64 (64 % 4 == 0: same XOR bits).
    const int r0s = t >> 2;
    const int cb0 = (((t & 3) ^ ((r0s >> 1) & 3)) << 4);
    const int voff0 = r0s * KB + cb0;            // shared by A and B panels
    const int voff1 = voff0 + 64 * KB;
    const uint8_t* Abase = A + m0 * (long)KB;    // uniform -> SGPR
    const uint8_t* Bbase = B + n0 * (long)KB;    // uniform -> SGPR
    const int lo0 = t * 16, lo1 = t * 16 + 4096;

    // ds_read offsets (swizzled, r2-proven XOR), per k-half h: c = h*2 + lh.
    auto swz = [](int r, int c) {
        return r * 64 + ((c ^ ((r >> 1) & 3)) << 4);
    };
    int offA[2][2], offB[2][2];
#pragma unroll
    for (int h = 0; h < 2; ++h) {
#pragma unroll
        for (int mt = 0; mt < 2; ++mt)
            offA[h][mt] = swz(wm * 64 + mt * 32 + lr, h * 2 + lh);
#pragma unroll
        for (int nt = 0; nt < 2; ++nt)
            offB[h][nt] = swz(wn * 64 + nt * 32 + lr, h * 2 + lh);
    }

    v16f acc[2][2] = {};   // 64 regs (AGPR-eligible)

    // Prologue: issue units 0..4; wait units 0,1 landed (10-6=4 loads done).
#pragma unroll
    for (int j = 0; j < 5; ++j) {
        int tj = j >> 1, slot = j;
        const uint8_t* s = (j & 1) ? Bbase : Abase;
        __builtin_amdgcn_global_load_lds(GLOBAL_AS(s + tj * 64 + voff0), LDS_AS(smem + slot * 8192 + lo0), 16, 0, 0);
        __builtin_amdgcn_global_load_lds(GLOBAL_AS(s + tj * 64 + voff1), LDS_AS(smem + slot * 8192 + lo1), 16, 0, 0);
    }
    asm volatile("s_waitcnt vmcnt(6)" ::: "memory");
    asm volatile("s_barrier" ::: "memory");

#pragma unroll 2
    for (int tau = 0; tau < 32; ++tau) {
        auto phase = [&](auto hc) {
            constexpr int h = decltype(hc)::value;
            const int sA = (2 * tau) & 7;
            const int sB = sA + 1;
            // Fragments in low half of v8i; high half undef (HW reads only
            // regs 0..3 for FMT=fp4 -- r4/r5/r6 exactness proves it).
            v8i ar8[2], br8[2];
#pragma unroll
            for (int mt = 0; mt < 2; ++mt) {
                v4i v = *(const v4i*)(smem + sA * 8192 + offA[h][mt]);
                ar8[mt] = __builtin_shufflevector(v, v, 0, 1, 2, 3, -1, -1, -1, -1);
            }
#pragma unroll
            for (int nt = 0; nt < 2; ++nt) {
                v4i v = *(const v4i*)(smem + sB * 8192 + offB[h][nt]);
                br8[nt] = __builtin_shufflevector(v, v, 0, 1, 2, 3, -1, -1, -1, -1);
            }
            // Stage unit j = 2*tau + h + 5 into slot j&7 (freed at phase j-3).
            {
                int j = 2 * tau + h + 5;
                if (j < 64) {
                    int tj = j >> 1, slot = j & 7;
                    const uint8_t* s = (j & 1) ? Bbase : Abase;
                    __builtin_amdgcn_global_load_lds(GLOBAL_AS(s + tj * 64 + voff0), LDS_AS(smem + slot * 8192 + lo0), 16, 0, 0);
                    __builtin_amdgcn_global_load_lds(GLOBAL_AS(s + tj * 64 + voff1), LDS_AS(smem + slot * 8192 + lo1), 16, 0, 0);
                }
            }
            asm volatile("s_barrier" ::: "memory");   // B1
            __builtin_amdgcn_s_setprio(1);
#pragma unroll
            for (int mt = 0; mt < 2; ++mt)
#pragma unroll
                for (int nt = 0; nt < 2; ++nt)
                    acc[mt][nt] = __builtin_amdgcn_mfma_scale_f32_32x32x64_f8f6f4(
                        ar8[mt], br8[nt], acc[mt][nt], 4, 4, 0, 0x7F7F7F7F, 0, 0x7F7F7F7F);
            __builtin_amdgcn_s_setprio(0);
            if constexpr (h == 1) {
                if (tau <= 28)      asm volatile("s_waitcnt vmcnt(6)" ::: "memory");
                else if (tau == 29) asm volatile("s_waitcnt vmcnt(4)" ::: "memory");
                else if (tau == 30) asm volatile("s_waitcnt vmcnt(0)" ::: "memory");
            }
            asm volatile("s_barrier" ::: "memory");   // B2
        };
        phase(IC<0>{});
        phase(IC<1>{});
    }

    // Epilogue: 32x32 C/D layout col = lane&31, row = (reg&3)+8*(reg>>2)+4*(lane>>5).
#pragma unroll
    for (int mt = 0; mt < 2; ++mt) {
        long rbase = m0 + wm * 64 + mt * 32 + 4 * lh;
#pragma unroll
        for (int nt = 0; nt < 2; ++nt) {
            long gcol = n0 + wn * 64 + nt * 32 + lr;
#pragma unroll
            for (int r = 0; r < 16; ++r) {
                long grow = rbase + (r & 3) + 8 * (r >> 2);
                C[grow * Nx + gcol] = acc[mt][nt][r];
            }
        }
    }
}

extern "C" void kernel_launch(void* const* d_in, const int* in_sizes, int n_in,
                              void* d_out, int out_size, void* d_ws, size_t ws_size,
                              hipStream_t stream) {
    const float* x = (const float*)d_in[0];
    const float* weight = (const float*)d_in[1];
    float* out = (float*)d_out;

    // Workspace: xq 16 MB | wq 32 MB | partials 16 KB | thr
    uint8_t* xq = (uint8_t*)d_ws;
    uint8_t* wq = xq + X_ELEMS / 2;
    double* partials = (double*)((char*)d_ws + X_ELEMS / 2 + W_ELEMS / 2);
    float* thr = (float*)((char*)d_ws + X_ELEMS / 2 + W_ELEMS / 2 + 2048 * sizeof(double));

    absum_kernel<<<2048, 256, 0, stream>>>((const float4*)weight, partials);
    finalize_kernel<<<1, 256, 0, stream>>>(partials, thr);
    quantw_kernel<<<8192, 256, 0, stream>>>((const float4*)weight, (uint4*)wq, thr);
    quantx_kernel<<<4096, 256, 0, stream>>>((const float4*)x, (uint4*)xq);
    gemm_fp4<<<8192, 256, 0, stream>>>(xq, wq, out);
}

// Round 9
// 571.230 us; speedup vs baseline: 2.9378x; 1.2102x over previous
//
#include <hip/hip_runtime.h>
#include <hip/hip_bf16.h>
#include <cstdint>

constexpr int Mx = 8192;
constexpr int Kx = 4096;
constexpr int Nx = 16384;
constexpr long W_ELEMS = (long)Nx * Kx;      // 67108864
constexpr long X_ELEMS = (long)Mx * Kx;      // 33554432
constexpr int KB = Kx / 2;                   // 2048 packed fp4 bytes per row

typedef int v4i __attribute__((ext_vector_type(4)));
typedef int v8i __attribute__((ext_vector_type(8)));
typedef float v16f __attribute__((ext_vector_type(16)));

#define GLOBAL_AS(p) ((const __attribute__((address_space(1))) void*)(p))
#define LDS_AS(p)    ((__attribute__((address_space(3))) void*)(p))

template <int P> struct IC { static constexpr int value = P; };

// ---------------- Pass 1: sum |W| (deterministic two-level tree) ----------------
__global__ __launch_bounds__(256) void absum_kernel(const float4* __restrict__ W4,
                                                    double* __restrict__ partials) {
    int t = threadIdx.x;
    long base = (long)blockIdx.x * 8192;
    double s = 0.0;
#pragma unroll 4
    for (int i = 0; i < 32; ++i) {
        float4 v = W4[base + (long)i * 256 + t];
        s += (double)fabsf(v.x) + (double)fabsf(v.y) +
             (double)fabsf(v.z) + (double)fabsf(v.w);
    }
    __shared__ double sm[256];
    sm[t] = s;
    __syncthreads();
    for (int off = 128; off > 0; off >>= 1) {
        if (t < off) sm[t] += sm[t + off];
        __syncthreads();
    }
    if (t == 0) partials[blockIdx.x] = sm[0];
}

__global__ __launch_bounds__(256) void finalize_kernel(const double* __restrict__ partials,
                                                       float* __restrict__ thr) {
    int t = threadIdx.x;
    double s = 0.0;
#pragma unroll
    for (int i = 0; i < 8; ++i) s += partials[(long)i * 256 + t];
    __shared__ double sm[256];
    sm[t] = s;
    __syncthreads();
    for (int off = 128; off > 0; off >>= 1) {
        if (t < off) sm[t] += sm[t + off];
        __syncthreads();
    }
    if (t == 0) {
        double gamma = sm[0] / (double)W_ELEMS + 1e-6;
        *thr = (float)(0.5 * gamma);
    }
}

// fp4 e2m1 encode of ternary: +1 -> 0x2, -1 -> 0xA, 0 -> 0x0
__device__ __forceinline__ uint32_t enc_t(float v, float thr) {
    return (fabsf(v) > thr) ? ((v > 0.f) ? 0x2u : 0xAu) : 0x0u;
}

__device__ __forceinline__ uint32_t pack8(float4 a, float4 b, float thr) {
    return enc_t(a.x, thr)        | (enc_t(a.y, thr) << 4)  |
          (enc_t(a.z, thr) << 8)  | (enc_t(a.w, thr) << 12) |
          (enc_t(b.x, thr) << 16) | (enc_t(b.y, thr) << 20) |
          (enc_t(b.z, thr) << 24) | (enc_t(b.w, thr) << 28);
}

// ---------------- Pass 2: quantize W -> packed fp4 (32 elems/thread) -----------
__global__ __launch_bounds__(256) void quantw_kernel(const float4* __restrict__ W4,
                                                     uint4* __restrict__ out,
                                                     const float* __restrict__ thrp) {
    float thr = *thrp;
    long gt = (long)blockIdx.x * 256 + threadIdx.x;
    uint32_t d0 = pack8(W4[gt * 8 + 0], W4[gt * 8 + 1], thr);
    uint32_t d1 = pack8(W4[gt * 8 + 2], W4[gt * 8 + 3], thr);
    uint32_t d2 = pack8(W4[gt * 8 + 4], W4[gt * 8 + 5], thr);
    uint32_t d3 = pack8(W4[gt * 8 + 6], W4[gt * 8 + 7], thr);
    out[gt] = make_uint4(d0, d1, d2, d3);
}

// ---------------- Pass 3: binarize x -> packed fp4 sign ------------------------
__global__ __launch_bounds__(256) void quantx_kernel(const float4* __restrict__ X4,
                                                     uint4* __restrict__ out) {
    long gt = (long)blockIdx.x * 256 + threadIdx.x;
    uint32_t d0 = pack8(X4[gt * 8 + 0], X4[gt * 8 + 1], 0.f);
    uint32_t d1 = pack8(X4[gt * 8 + 2], X4[gt * 8 + 3], 0.f);
    uint32_t d2 = pack8(X4[gt * 8 + 4], X4[gt * 8 + 5], 0.f);
    uint32_t d3 = pack8(X4[gt * 8 + 6], X4[gt * 8 + 7], 0.f);
    out[gt] = make_uint4(d0, d1, d2, d3);
}

// ---------------- Pass 4: fp4 GEMM, 256^2 tile, mfma_scale 32x32x64 ------------
// r6 schedule (proven 384 us, absmax 0) with ONE change: B1 removed.
// Safety re-derivation (single B2 barrier per phase):
//  - a phase reads slots (2tau)&7,(2tau+1)&7 and stages into (2tau+h+5)&7:
//    indices differ by 4..6 mod 8, never equal -> lagging waves' reads never
//    touch the slot a leading wave stages into;
//  - stage target slot last held unit (2tau+h-3), last read at phase
//    (tau-2,h), >=2 barrier crossings before the stage issues;
//  - data-readiness: per-wave vmcnt(6) precedes its B2 arrival -> after B2,
//    all waves' slices of units <= 2tau+1 are in LDS (unchanged from r6).
// Effect: waves drift within the phase body -> one wave's MFMA burst overlaps
// other waves' ds_read bursts on the same SIMD (LDS pipe || MFMA pipe).
__global__ __launch_bounds__(512) void gemm_fp4(const uint8_t* __restrict__ A,
                                                const uint8_t* __restrict__ B,
                                                float* __restrict__ C) {
    __shared__ __align__(16) uint8_t smem[8 * 16384];   // 128 KiB

    const int t = threadIdx.x;
    const int l = t & 63;
    const int wid = t >> 6;
    const int wm = wid >> 2;          // 0..1
    const int wn = wid & 3;           // 0..3
    const int lr = l & 31;            // row within 32
    const int lh = l >> 5;            // k-chunk selector

    // Bijective XCD swizzle: 2048 wgs % 8 == 0.
    int wg = blockIdx.x;
    int sw = (wg & 7) * 256 + (wg >> 3);
    int bm = sw & 31;                 // 32 M-tiles
    int bn = sw >> 5;                 // 64 N-tiles
    const long m0 = (long)bm * 256;
    const long n0 = (long)bn * 256;

    // Staging: phys chunk cp holds row r = cp>>2, logical col c = (cp&3)^((r>>1)&3).
    // cp0 = t, cp1 = t+512 (row + 128: same XOR since 128 % 4 == 0).
    const int r0s = t >> 2;
    const int cb0 = (((t & 3) ^ ((r0s >> 1) & 3)) << 4);
    const int voff0 = r0s * KB + cb0;            // shared by A and B panels
    const int voff1 = voff0 + 128 * KB;
    const uint8_t* Abase = A + m0 * (long)KB;    // uniform -> SGPR
    const uint8_t* Bbase = B + n0 * (long)KB;    // uniform -> SGPR
    const int lo0 = t * 16, lo1 = t * 16 + 8192;

    // ds_read offsets (swizzled), per k-half h: c = h*2 + lh.
    auto swz = [](int r, int c) {
        return r * 64 + ((c ^ ((r >> 1) & 3)) << 4);
    };
    int offA[2][4], offB[2][2];
#pragma unroll
    for (int h = 0; h < 2; ++h) {
#pragma unroll
        for (int mt = 0; mt < 4; ++mt)
            offA[h][mt] = swz(wm * 128 + mt * 32 + lr, h * 2 + lh);
#pragma unroll
        for (int nt = 0; nt < 2; ++nt)
            offB[h][nt] = swz(wn * 64 + nt * 32 + lr, h * 2 + lh);
    }

    v16f acc[4][2] = {};   // 128 regs (AGPR-eligible)

    // Prologue: issue units 0..4; wait units 0,1 landed (10-4=6 outstanding).
#pragma unroll
    for (int j = 0; j < 5; ++j) {
        int tj = j >> 1, slot = j;
        const uint8_t* s = (j & 1) ? Bbase : Abase;
        __builtin_amdgcn_global_load_lds(GLOBAL_AS(s + tj * 64 + voff0), LDS_AS(smem + slot * 16384 + lo0), 16, 0, 0);
        __builtin_amdgcn_global_load_lds(GLOBAL_AS(s + tj * 64 + voff1), LDS_AS(smem + slot * 16384 + lo1), 16, 0, 0);
    }
    asm volatile("s_waitcnt vmcnt(6)" ::: "memory");
    asm volatile("s_barrier" ::: "memory");

#pragma unroll 2
    for (int tau = 0; tau < 32; ++tau) {
        auto phase = [&](auto hc) {
            constexpr int h = decltype(hc)::value;
            const int sA = (2 * tau) & 7;
            const int sB = sA + 1;
            // Fragments in low half of v8i; high half undef (HW reads only
            // regs 0..3 for FMT=fp4 -- r4/r5/r6 exactness proves it).
            v8i ar8[4], br8[2];
#pragma unroll
            for (int mt = 0; mt < 4; ++mt) {
                v4i v = *(const v4i*)(smem + sA * 16384 + offA[h][mt]);
                ar8[mt] = __builtin_shufflevector(v, v, 0, 1, 2, 3, -1, -1, -1, -1);
            }
#pragma unroll
            for (int nt = 0; nt < 2; ++nt) {
                v4i v = *(const v4i*)(smem + sB * 16384 + offB[h][nt]);
                br8[nt] = __builtin_shufflevector(v, v, 0, 1, 2, 3, -1, -1, -1, -1);
            }
            // Stage unit j = 2*tau + h + 5 into slot j&7 (freed at phase j-3).
            {
                int j = 2 * tau + h + 5;
                if (j < 64) {
                    int tj = j >> 1, slot = j & 7;
                    const uint8_t* s = (j & 1) ? Bbase : Abase;
                    __builtin_amdgcn_global_load_lds(GLOBAL_AS(s + tj * 64 + voff0), LDS_AS(smem + slot * 16384 + lo0), 16, 0, 0);
                    __builtin_amdgcn_global_load_lds(GLOBAL_AS(s + tj * 64 + voff1), LDS_AS(smem + slot * 16384 + lo1), 16, 0, 0);
                }
            }
            // (B1 removed -- waves drift; reads of lagging waves overlap MFMAs
            // of leading waves.  Slot-disjointness proof in header comment.)
            __builtin_amdgcn_s_setprio(1);
#pragma unroll
            for (int mt = 0; mt < 4; ++mt)
#pragma unroll
                for (int nt = 0; nt < 2; ++nt)
                    acc[mt][nt] = __builtin_amdgcn_mfma_scale_f32_32x32x64_f8f6f4(
                        ar8[mt], br8[nt], acc[mt][nt], 4, 4, 0, 0x7F7F7F7F, 0, 0x7F7F7F7F);
            __builtin_amdgcn_s_setprio(0);
            if constexpr (h == 1) {
                if (tau <= 28)      asm volatile("s_waitcnt vmcnt(6)" ::: "memory");
                else if (tau == 29) asm volatile("s_waitcnt vmcnt(4)" ::: "memory");
                else if (tau == 30) asm volatile("s_waitcnt vmcnt(0)" ::: "memory");
            }
            asm volatile("s_barrier" ::: "memory");   // B2
        };
        phase(IC<0>{});
        phase(IC<1>{});
    }

    // Epilogue: 32x32 C/D layout col = lane&31, row = (reg&3)+8*(reg>>2)+4*(lane>>5).
#pragma unroll
    for (int mt = 0; mt < 4; ++mt) {
        long rbase = m0 + wm * 128 + mt * 32 + 4 * lh;
#pragma unroll
        for (int nt = 0; nt < 2; ++nt) {
            long gcol = n0 + wn * 64 + nt * 32 + lr;
#pragma unroll
            for (int r = 0; r < 16; ++r) {
                long grow = rbase + (r & 3) + 8 * (r >> 2);
                C[grow * Nx + gcol] = acc[mt][nt][r];
            }
        }
    }
}

extern "C" void kernel_launch(void* const* d_in, const int* in_sizes, int n_in,
                              void* d_out, int out_size, void* d_ws, size_t ws_size,
                              hipStream_t stream) {
    const float* x = (const float*)d_in[0];
    const float* weight = (const float*)d_in[1];
    float* out = (float*)d_out;

    // Workspace: xq 16 MB | wq 32 MB | partials 16 KB | thr
    uint8_t* xq = (uint8_t*)d_ws;
    uint8_t* wq = xq + X_ELEMS / 2;
    double* partials = (double*)((char*)d_ws + X_ELEMS / 2 + W_ELEMS / 2);
    float* thr = (float*)((char*)d_ws + X_ELEMS / 2 + W_ELEMS / 2 + 2048 * sizeof(double));

    absum_kernel<<<2048, 256, 0, stream>>>((const float4*)weight, partials);
    finalize_kernel<<<1, 256, 0, stream>>>(partials, thr);
    quantw_kernel<<<8192, 256, 0, stream>>>((const float4*)weight, (uint4*)wq, thr);
    quantx_kernel<<<4096, 256, 0, stream>>>((const float4*)x, (uint4*)xq);
    gemm_fp4<<<2048, 512, 0, stream>>>(xq, wq, out);
}